// Round 8
// baseline (60.929 us; speedup 1.0000x reference)
//
#include <hip/hip_runtime.h>

#define NCLS 24
#define NB 8
#define NCH 128
#define WLO 128
#define WHI 512
#define CELLS (128*128)
#define SUBS 2                      // subtiles per block, register-accumulated
#define BPB 128                     // blocks per batch
#define NBLK (NB * BPB)             // 1024
#define KCH (NCLS * NCH)            // 3072
#define NF (NB * KCH)               // 24576
#define REP 3                       // DIAGNOSTIC: repeat body so fm_main > 40us -> visible in rocprof top-5

typedef _Float16 f16x4 __attribute__((ext_vector_type(4)));
typedef _Float16 f16x8 __attribute__((ext_vector_type(8)));
typedef float    f32x4 __attribute__((ext_vector_type(4)));

// hist row swizzle: cell ^ ((cls&7)<<3), 8-cell (32 B) granularity.
#define HSWZ(c_, e_) ((e_) ^ (((c_) & 7) << 3))

// One block = one 128-cell row = 2 subtiles of 64 cells, acc carried in regs.
__global__ __launch_bounds__(256, 4)
void fm_main(const float* __restrict__ data, const int* __restrict__ label,
             _Float16* __restrict__ part, float* __restrict__ cpart)
{
    __shared__ float    histf[32 * 64];       // 8 KB, rows 24-31 stay zero (A-pad)
    __shared__ _Float16 tile[NCH * 64];       // 16 KB, [ch][cell swz]

    const int bid  = blockIdx.x;
    const int b    = bid >> 7;
    const int grp  = bid & 127;               // cell row
    const int tid  = threadIdx.x;

    const int q    = tid & 15;        // float4 slot (4 cells)
    const int chb  = tid >> 4;        // channel base 0..15
    const int r    = tid >> 6;        // label hi-res row 0..3
    const int cl   = tid & 63;        // label cell 0..63
    const int w    = tid >> 6;        // wave id
    const int lane = tid & 63;

    const float* dbase = data  + (size_t)b * NCH * CELLS;
    const int*   lbase = label + (size_t)b * (WHI * WHI) + (size_t)(4 * grp + r) * WHI;

    for (int rep = 0; rep < REP; ++rep) {     // DIAGNOSTIC loop: reps identical, same flush values
        // ---- prologue: issue subtile-0 loads ----
        float4 v[8];
        int4 lv;
        {
            const int cb = grp * WLO;                 // x0 = 0
#pragma unroll
            for (int k = 0; k < 8; ++k)
                v[k] = *reinterpret_cast<const float4*>(dbase + (size_t)(chb + k * 16) * CELLS + cb + q * 4);
            lv = *reinterpret_cast<const int4*>(lbase + cl * 4);
        }

        f32x4 acc[2][2];
#pragma unroll
        for (int mt = 0; mt < 2; ++mt)
#pragma unroll
            for (int nt = 0; nt < 2; ++nt) acc[mt][nt] = (f32x4){0.f, 0.f, 0.f, 0.f};
        float cs0 = 0.f, cs1 = 0.f;

#pragma unroll
        for (int s = 0; s < SUBS; ++s) {
            // ---- zero histogram ----
#pragma unroll
            for (int k = 0; k < 8; ++k) histf[tid + k * 256] = 0.f;
            __syncthreads();

            // ---- histogram atomics (distinct cell per lane) ----
            if ((unsigned)lv.x < 24u) atomicAdd(&histf[lv.x * 64 + HSWZ(lv.x, cl)], 1.f);
            if ((unsigned)lv.y < 24u) atomicAdd(&histf[lv.y * 64 + HSWZ(lv.y, cl)], 1.f);
            if ((unsigned)lv.z < 24u) atomicAdd(&histf[lv.z * 64 + HSWZ(lv.z, cl)], 1.f);
            if ((unsigned)lv.w < 24u) atomicAdd(&histf[lv.w * 64 + HSWZ(lv.w, cl)], 1.f);

            // ---- stage f16 data tile, swizzled [ch][cell] ----
#pragma unroll
            for (int k = 0; k < 8; ++k) {
                const int ch = chb + k * 16;
                f16x4 hv;
                hv[0] = (_Float16)v[k].x; hv[1] = (_Float16)v[k].y;
                hv[2] = (_Float16)v[k].z; hv[3] = (_Float16)v[k].w;
                const int idx = ch * 64 + ((((q >> 1) ^ (ch & 7)) << 3) | ((q & 1) << 2));
                *reinterpret_cast<f16x4*>(&tile[idx]) = hv;
            }

            // ---- prefetch subtile s+1 (latency hides under MFMA phase) ----
            if (s + 1 < SUBS) {
                const int cb = grp * WLO + 64;            // x0 = 64
#pragma unroll
                for (int k = 0; k < 8; ++k)
                    v[k] = *reinterpret_cast<const float4*>(dbase + (size_t)(chb + k * 16) * CELLS + cb + q * 4);
                lv = *reinterpret_cast<const int4*>(lbase + 256 + cl * 4);
            }
            __syncthreads();

            // ---- A fragments from f32 histogram; count partials from same reads ----
            f16x8 af[2][2];
#pragma unroll
            for (int mt = 0; mt < 2; ++mt)
#pragma unroll
                for (int kt = 0; kt < 2; ++kt) {
                    const int cls = mt * 16 + (lane & 15);
                    const int e0  = kt * 32 + (lane >> 4) * 8;
                    const float* hp = &histf[cls * 64 + HSWZ(cls, e0)];
                    const f32x4 h0 = *reinterpret_cast<const f32x4*>(hp);
                    const f32x4 h1 = *reinterpret_cast<const f32x4*>(hp + 4);
                    f16x8 a;
                    a[0] = (_Float16)h0.x; a[1] = (_Float16)h0.y; a[2] = (_Float16)h0.z; a[3] = (_Float16)h0.w;
                    a[4] = (_Float16)h1.x; a[5] = (_Float16)h1.y; a[6] = (_Float16)h1.z; a[7] = (_Float16)h1.w;
                    af[mt][kt] = a;
                    const float p = (h0.x + h0.y) + (h0.z + h0.w) + (h1.x + h1.y) + (h1.z + h1.w);
                    if (mt == 0) cs0 += p; else cs1 += p;
                }

            // ---- B fragments from tile ----
            f16x8 bf[2][2];
#pragma unroll
            for (int nt = 0; nt < 2; ++nt)
#pragma unroll
                for (int kt = 0; kt < 2; ++kt) {
                    const int row = w * 32 + nt * 16 + (lane & 15);
                    const int g   = kt * 4 + (lane >> 4);
                    bf[nt][kt] = *reinterpret_cast<const f16x8*>(&tile[row * 64 + ((g ^ (row & 7)) << 3)]);
                }

            // ---- 8 MFMAs, accumulate across subtiles ----
#pragma unroll
            for (int mt = 0; mt < 2; ++mt)
#pragma unroll
                for (int nt = 0; nt < 2; ++nt)
#pragma unroll
                    for (int kt = 0; kt < 2; ++kt)
                        acc[mt][nt] = __builtin_amdgcn_mfma_f32_16x16x32_f16(
                            af[mt][kt], bf[nt][kt], acc[mt][nt], 0, 0, 0);

            __syncthreads();   // protect hist/tile before re-zero (needed every iter incl. rep wrap)
        }

        // ---- counts: butterfly over 4 k-groups; wave 0 lanes write ----
        cs0 += __shfl_xor(cs0, 16, 64); cs0 += __shfl_xor(cs0, 32, 64);
        cs1 += __shfl_xor(cs1, 16, 64); cs1 += __shfl_xor(cs1, 32, 64);
        if (w == 0 && lane < 16) {
            cpart[(size_t)bid * NCLS + lane] = cs0;
            if (lane < 8) cpart[(size_t)bid * NCLS + 16 + lane] = cs1;
        }

        // ---- flush f16 per-block partials (non-atomic; same values every rep) ----
        _Float16* pblk = part + (size_t)bid * KCH;
#pragma unroll
        for (int mt = 0; mt < 2; ++mt)
#pragma unroll
            for (int nt = 0; nt < 2; ++nt)
#pragma unroll
                for (int rg = 0; rg < 4; ++rg) {
                    const int cls = mt * 16 + (lane >> 4) * 4 + rg;   // C/D: row=(lane>>4)*4+reg
                    const int ch  = w * 32 + nt * 16 + (lane & 15);   //      col=lane&15
                    if (cls < NCLS) pblk[cls * NCH + ch] = (_Float16)acc[mt][nt][rg];
                }
    }
}

// Grid 384 = (b, cls, ch-half). 4 waves reduce 32 g's each -> LDS -> wave-0 finish.
__global__ __launch_bounds__(256)
void fm_final(const _Float16* __restrict__ part, const float* __restrict__ cpart,
              float* __restrict__ out)
{
    __shared__ float red[256];
    __shared__ float credv[128];
    const int bid  = blockIdx.x;
    const int b    = bid / (NCLS * 2);
    const int rem  = bid % (NCLS * 2);
    const int cls  = rem >> 1;
    const int half = rem & 1;
    const int t    = threadIdx.x;
    const int c    = t & 63;           // channel within half
    const int gq   = t >> 6;           // g-quarter 0..3

    if (t < 128) credv[t] = cpart[(size_t)(b * BPB + t) * NCLS + cls];

    const _Float16* pb = part + (size_t)(b * BPB + gq * 32) * KCH + cls * NCH + half * 64 + c;
    float s = 0.f;
#pragma unroll 8
    for (int g = 0; g < 32; ++g) s += (float)pb[(size_t)g * KCH];
    red[t] = s;
    __syncthreads();

    if (t < 64) {
        float cnt = credv[t] + credv[t + 64];
#pragma unroll
        for (int o = 32; o >= 1; o >>= 1) cnt += __shfl_xor(cnt, o, 64);
        const float sf = red[t] + red[t + 64] + red[t + 128] + red[t + 192];
        out[(size_t)b * KCH + (half * 64 + t) * NCLS + cls] = sf / (cnt + 1e-8f);  // (B,C,NCLS)
        if (t == 0 && half == 0) out[NF + b * NCLS + cls] = (cnt > 0.f) ? 1.f : 0.f;
    }
}

extern "C" void kernel_launch(void* const* d_in, const int* in_sizes, int n_in,
                              void* d_out, int out_size, void* d_ws, size_t ws_size,
                              hipStream_t stream) {
    const float* data  = (const float*)d_in[0];
    const int*   label = (const int*)d_in[1];
    float*     out   = (float*)d_out;
    _Float16*  part  = (_Float16*)d_ws;                          // NBLK*3072 f16 (6.3 MB)
    float*     cpart = (float*)(part + (size_t)NBLK * KCH);      // NBLK*24 f32

    fm_main<<<dim3(NBLK), dim3(256), 0, stream>>>(data, label, part, cpart);
    fm_final<<<dim3(NB * NCLS * 2), dim3(256), 0, stream>>>(part, cpart, out);
}

// Round 9
// 26.881 us; speedup vs baseline: 2.2666x; 2.2666x over previous
//
#include <hip/hip_runtime.h>

#define NCLS 24
#define NB 8
#define NCH 128
#define WLO 128
#define WHI 512
#define CELLS (128*128)
#define SUBS 2                      // subtiles per block, register-accumulated
#define BPB 128                     // blocks per batch
#define NBLK (NB * BPB)             // 1024
#define KCH (NCLS * NCH)            // 3072
#define NF (NB * KCH)               // 24576

typedef _Float16 f16x4 __attribute__((ext_vector_type(4)));
typedef _Float16 f16x8 __attribute__((ext_vector_type(8)));
typedef float    f32x4 __attribute__((ext_vector_type(4)));

// hist row swizzle: cell ^ ((cls&7)<<3), 8-cell (32 B) granularity.
#define HSWZ(c_, e_) ((e_) ^ (((c_) & 7) << 3))

// Barrier WITHOUT the vmcnt(0) drain __syncthreads() forces: drain LDS ops
// (visibility across waves) but let in-flight global prefetches ride through.
__device__ __forceinline__ void barrier_nodrain() {
    asm volatile("s_waitcnt lgkmcnt(0)" ::: "memory");
    __builtin_amdgcn_s_barrier();
}

// One block = one 128-cell row = 2 subtiles of 64 cells, acc carried in regs.
__global__ __launch_bounds__(256, 4)
void fm_main(const float* __restrict__ data, const int* __restrict__ label,
             _Float16* __restrict__ part, float* __restrict__ cpart)
{
    __shared__ float    histf[32 * 64];       // 8 KB, rows 24-31 stay zero (A-pad)
    __shared__ _Float16 tile[NCH * 64];       // 16 KB, [ch][cell swz]

    const int bid  = blockIdx.x;
    const int b    = bid >> 7;
    const int grp  = bid & 127;               // cell row
    const int tid  = threadIdx.x;

    const int q    = tid & 15;        // float4 slot (4 cells)
    const int chb  = tid >> 4;        // channel base 0..15
    const int r    = tid >> 6;        // label hi-res row 0..3
    const int cl   = tid & 63;        // label cell 0..63
    const int w    = tid >> 6;        // wave id
    const int lane = tid & 63;

    const float* dbase = data  + (size_t)b * NCH * CELLS;
    const int*   lbase = label + (size_t)b * (WHI * WHI) + (size_t)(4 * grp + r) * WHI;

    // ---- prologue: label FIRST (its consumer runs first), then data loads ----
    float4 v[8];
    int4 lv;
    {
        const int cb = grp * WLO;                 // x0 = 0
        lv = *reinterpret_cast<const int4*>(lbase + cl * 4);
#pragma unroll
        for (int k = 0; k < 8; ++k)
            v[k] = *reinterpret_cast<const float4*>(dbase + (size_t)(chb + k * 16) * CELLS + cb + q * 4);
    }

    f32x4 acc[2][2];
#pragma unroll
    for (int mt = 0; mt < 2; ++mt)
#pragma unroll
        for (int nt = 0; nt < 2; ++nt) acc[mt][nt] = (f32x4){0.f, 0.f, 0.f, 0.f};
    float cs0 = 0.f, cs1 = 0.f;

#pragma unroll
    for (int s = 0; s < SUBS; ++s) {
        // ---- zero histogram ----
#pragma unroll
        for (int k = 0; k < 8; ++k) histf[tid + k * 256] = 0.f;
        barrier_nodrain();                    // B1: prefetched globals stay in flight

        // ---- histogram atomics (compiler waits vmcnt for lv at first use) ----
        if ((unsigned)lv.x < 24u) atomicAdd(&histf[lv.x * 64 + HSWZ(lv.x, cl)], 1.f);
        if ((unsigned)lv.y < 24u) atomicAdd(&histf[lv.y * 64 + HSWZ(lv.y, cl)], 1.f);
        if ((unsigned)lv.z < 24u) atomicAdd(&histf[lv.z * 64 + HSWZ(lv.z, cl)], 1.f);
        if ((unsigned)lv.w < 24u) atomicAdd(&histf[lv.w * 64 + HSWZ(lv.w, cl)], 1.f);

        // ---- stage f16 data tile, swizzled [ch][cell] ----
#pragma unroll
        for (int k = 0; k < 8; ++k) {
            const int ch = chb + k * 16;
            f16x4 hv;
            hv[0] = (_Float16)v[k].x; hv[1] = (_Float16)v[k].y;
            hv[2] = (_Float16)v[k].z; hv[3] = (_Float16)v[k].w;
            const int idx = ch * 64 + ((((q >> 1) ^ (ch & 7)) << 3) | ((q & 1) << 2));
            *reinterpret_cast<f16x4*>(&tile[idx]) = hv;
        }

        // ---- prefetch subtile s+1: label first, then data; rides through B2/B3/B1 ----
        if (s + 1 < SUBS) {
            const int cb = grp * WLO + 64;            // x0 = 64
            lv = *reinterpret_cast<const int4*>(lbase + 256 + cl * 4);
#pragma unroll
            for (int k = 0; k < 8; ++k)
                v[k] = *reinterpret_cast<const float4*>(dbase + (size_t)(chb + k * 16) * CELLS + cb + q * 4);
        }
        barrier_nodrain();                    // B2: NO vmcnt drain (the R6 killer)

        // ---- A fragments from f32 histogram; count partials from same reads ----
        f16x8 af[2][2];
#pragma unroll
        for (int mt = 0; mt < 2; ++mt)
#pragma unroll
            for (int kt = 0; kt < 2; ++kt) {
                const int cls = mt * 16 + (lane & 15);
                const int e0  = kt * 32 + (lane >> 4) * 8;
                const float* hp = &histf[cls * 64 + HSWZ(cls, e0)];
                const f32x4 h0 = *reinterpret_cast<const f32x4*>(hp);
                const f32x4 h1 = *reinterpret_cast<const f32x4*>(hp + 4);
                f16x8 a;
                a[0] = (_Float16)h0.x; a[1] = (_Float16)h0.y; a[2] = (_Float16)h0.z; a[3] = (_Float16)h0.w;
                a[4] = (_Float16)h1.x; a[5] = (_Float16)h1.y; a[6] = (_Float16)h1.z; a[7] = (_Float16)h1.w;
                af[mt][kt] = a;
                const float p = (h0.x + h0.y) + (h0.z + h0.w) + (h1.x + h1.y) + (h1.z + h1.w);
                if (mt == 0) cs0 += p; else cs1 += p;
            }

        // ---- B fragments from tile ----
        f16x8 bf[2][2];
#pragma unroll
        for (int nt = 0; nt < 2; ++nt)
#pragma unroll
            for (int kt = 0; kt < 2; ++kt) {
                const int row = w * 32 + nt * 16 + (lane & 15);
                const int g   = kt * 4 + (lane >> 4);
                bf[nt][kt] = *reinterpret_cast<const f16x8*>(&tile[row * 64 + ((g ^ (row & 7)) << 3)]);
            }

        // ---- 8 MFMAs, accumulate across subtiles ----
#pragma unroll
        for (int mt = 0; mt < 2; ++mt)
#pragma unroll
            for (int nt = 0; nt < 2; ++nt)
#pragma unroll
                for (int kt = 0; kt < 2; ++kt)
                    acc[mt][nt] = __builtin_amdgcn_mfma_f32_16x16x32_f16(
                        af[mt][kt], bf[nt][kt], acc[mt][nt], 0, 0, 0);

        barrier_nodrain();                    // B3: frag reads retired; prefetch still in flight
    }

    // ---- counts: butterfly over 4 k-groups; wave 0 lanes write ----
    cs0 += __shfl_xor(cs0, 16, 64); cs0 += __shfl_xor(cs0, 32, 64);
    cs1 += __shfl_xor(cs1, 16, 64); cs1 += __shfl_xor(cs1, 32, 64);
    if (w == 0 && lane < 16) {
        cpart[(size_t)bid * NCLS + lane] = cs0;
        if (lane < 8) cpart[(size_t)bid * NCLS + 16 + lane] = cs1;
    }

    // ---- flush f16 per-block partials (non-atomic) ----
    _Float16* pblk = part + (size_t)bid * KCH;
#pragma unroll
    for (int mt = 0; mt < 2; ++mt)
#pragma unroll
        for (int nt = 0; nt < 2; ++nt)
#pragma unroll
            for (int rg = 0; rg < 4; ++rg) {
                const int cls = mt * 16 + (lane >> 4) * 4 + rg;   // C/D: row=(lane>>4)*4+reg
                const int ch  = w * 32 + nt * 16 + (lane & 15);   //      col=lane&15
                if (cls < NCLS) pblk[cls * NCH + ch] = (_Float16)acc[mt][nt][rg];
            }
}

// Grid 384 = (b, cls, ch-half). 4 waves reduce 32 g's each -> LDS -> wave-0 finish.
__global__ __launch_bounds__(256)
void fm_final(const _Float16* __restrict__ part, const float* __restrict__ cpart,
              float* __restrict__ out)
{
    __shared__ float red[256];
    __shared__ float credv[128];
    const int bid  = blockIdx.x;
    const int b    = bid / (NCLS * 2);
    const int rem  = bid % (NCLS * 2);
    const int cls  = rem >> 1;
    const int half = rem & 1;
    const int t    = threadIdx.x;
    const int c    = t & 63;           // channel within half
    const int gq   = t >> 6;           // g-quarter 0..3

    if (t < 128) credv[t] = cpart[(size_t)(b * BPB + t) * NCLS + cls];

    const _Float16* pb = part + (size_t)(b * BPB + gq * 32) * KCH + cls * NCH + half * 64 + c;
    float s = 0.f;
#pragma unroll 8
    for (int g = 0; g < 32; ++g) s += (float)pb[(size_t)g * KCH];
    red[t] = s;
    __syncthreads();

    if (t < 64) {
        float cnt = credv[t] + credv[t + 64];
#pragma unroll
        for (int o = 32; o >= 1; o >>= 1) cnt += __shfl_xor(cnt, o, 64);
        const float sf = red[t] + red[t + 64] + red[t + 128] + red[t + 192];
        out[(size_t)b * KCH + (half * 64 + t) * NCLS + cls] = sf / (cnt + 1e-8f);  // (B,C,NCLS)
        if (t == 0 && half == 0) out[NF + b * NCLS + cls] = (cnt > 0.f) ? 1.f : 0.f;
    }
}

extern "C" void kernel_launch(void* const* d_in, const int* in_sizes, int n_in,
                              void* d_out, int out_size, void* d_ws, size_t ws_size,
                              hipStream_t stream) {
    const float* data  = (const float*)d_in[0];
    const int*   label = (const int*)d_in[1];
    float*     out   = (float*)d_out;
    _Float16*  part  = (_Float16*)d_ws;                          // NBLK*3072 f16 (6.3 MB)
    float*     cpart = (float*)(part + (size_t)NBLK * KCH);      // NBLK*24 f32

    fm_main<<<dim3(NBLK), dim3(256), 0, stream>>>(data, label, part, cpart);
    fm_final<<<dim3(NB * NCLS * 2), dim3(256), 0, stream>>>(part, cpart, out);
}